// Round 4
// baseline (180.656 us; speedup 1.0000x reference)
//
#include <hip/hip_runtime.h>

// Div (quantized qint16) vs float64 numpy reference.
//
// out = clip(round(q1*s1 * (recip_q(q2*s2)*TS) / os)), recip_q = piecewise
// {const, line, dense LUT(256), sparse LUT(256), line, const} of 1/|x|, signed.
//
// r3 passed (absmax 384) with per-element f64 piecewise math but was
// LATENCY-bound: VALUBusy 25%, HBM 35%, dur 164us vs ~128us roofline -- the
// ~16-op dependent f64 chain + f64 LDS gather per element stalls 8 waves/SIMD.
//
// Fix: recip_q depends ONLY on |q2| (<= 32768 distinct values). Hoist r3's
// exact f64 piecewise computation into a per-block uint16 LUT[32768] in LDS
// (rq values are integers in [15,32767] -> uint16-exact; |q2|=32768 clamps to
// 32767 which provably yields the same sparse index 236 -> same rq).
// Hot loop per element: min(abs,32767) -> ds_read_u16 -> sign -> 2 f32 muls +
// rintf + clamp. f32 finals move the rounding decision by <=0.007 abs ->
// at most +-1 output unit vs r3 (threshold 655, r3 margin 271).
//
// 64 KiB LDS/block -> 2 blocks/CU; 1024-thr blocks -> 32 waves/CU (full occ).
// 512 blocks co-resident, 32 int4 grid-stride iters each. Memory-bound:
// 512 MiB read + 256 MiB write -> ~128 us @ 6.3 TB/s.

#define TS64  (2.0 / 0.01 / 65535.0)     // == f64 of Python 2/0.01/65535 (200/65535)
#define STEPD (0.99 / 255.0)
#define STEPS (6.0 / 255.0)

__device__ __forceinline__ double quant64(double y) {
    return fmin(fmax(rint(y / TS64), -32768.0), 32767.0);
}

// r3's proven f64 piecewise recip-quant, evaluated per |q2| value (aq >= 0).
__device__ double rq_of_aq(int aq, double s2d) {
    const double ax = (double)aq * s2d;            // EXACT in f64 (41-bit product)
    double rq;
    if (ax < 0.01) {
        rq = 32767.0;                    // left const + left line both saturate
    } else if (ax < 7.0) {
        const bool dense = ax < 1.0;
        const double xmin = dense ? 0.01 : 1.0;
        const double step = dense ? STEPD : STEPS;
        double idx = rint((ax - xmin) / step);     // IEEE f64 divide
        idx = fmin(fmax(idx, 0.0), 255.0);
        double xs;
        if (idx == 255.0) {
            xs = dense ? 1.0 : 7.0;                // np.linspace endpoint overwrite
        } else {
            double p = idx * step;                 // linspace: round product first,
            asm volatile("" : "+v"(p));            // block fma contraction,
            xs = xmin + p;                         // then add start
        }
        rq = quant64(1.0 / xs);
    } else if (ax < 20.0) {
        rq = quant64(1.0 / 7.0 + (ax - 7.0) * ((0.05 - 1.0 / 7.0) / 13.0));
    } else {
        rq = 16.0;                                 // quant(1/20)
    }
    return rq;
}

__device__ __forceinline__ void build_lut(unsigned short* tbl, const float* s2p) {
    const double s2d = (double)s2p[0];
    for (int t = threadIdx.x; t < 32768; t += (int)blockDim.x)
        tbl[t] = (unsigned short)(int)rq_of_aq(t, s2d);
    __syncthreads();
}

__device__ __forceinline__ float elem(int a, int b, float kf,
                                      const unsigned short* tbl) {
    const int aq = min(abs(b), 32767);   // |q2|=32768 -> same rq as 32767 (idx 236)
    float rq = (float)tbl[aq];           // ds_read_u16, exact int in [15,32767]
    rq = (b < 0) ? -rq : rq;
    const float o = rintf((float)a * kf * rq);
    return fminf(fmaxf(o, -32768.0f), 32767.0f);
}

__global__ void __launch_bounds__(1024)
div_q16_main(const int4* __restrict__ q1, const int4* __restrict__ q2,
             const float* __restrict__ s1p, const float* __restrict__ s2p,
             const float* __restrict__ osp, float4* __restrict__ out, int nvec) {
    __shared__ unsigned short tbl[32768];          // 64 KiB
    build_lut(tbl, s2p);
    const float kf = (float)((double)s1p[0] * TS64 / (double)osp[0]);
    const int stride = gridDim.x * blockDim.x;
    for (int i = blockIdx.x * blockDim.x + threadIdx.x; i < nvec; i += stride) {
        const int4 a = q1[i];
        const int4 b = q2[i];
        float4 o;
        o.x = elem(a.x, b.x, kf, tbl);
        o.y = elem(a.y, b.y, kf, tbl);
        o.z = elem(a.z, b.z, kf, tbl);
        o.w = elem(a.w, b.w, kf, tbl);
        out[i] = o;
    }
}

__global__ void __launch_bounds__(1024)
div_q16_tail(const int* __restrict__ q1, const int* __restrict__ q2,
             const float* __restrict__ s1p, const float* __restrict__ s2p,
             const float* __restrict__ osp, float* __restrict__ out,
             int base, int n) {
    __shared__ unsigned short tbl[32768];
    build_lut(tbl, s2p);
    const float kf = (float)((double)s1p[0] * TS64 / (double)osp[0]);
    const int i = base + blockIdx.x * (int)blockDim.x + threadIdx.x;
    if (i < n) out[i] = elem(q1[i], q2[i], kf, tbl);
}

extern "C" void kernel_launch(void* const* d_in, const int* in_sizes, int n_in,
                              void* d_out, int out_size, void* d_ws, size_t ws_size,
                              hipStream_t stream) {
    const int n = in_sizes[0];
    const int* q1 = (const int*)d_in[0];
    const int* q2 = (const int*)d_in[1];
    const float* s1 = (const float*)d_in[2];
    const float* s2 = (const float*)d_in[3];
    const float* os = (const float*)d_in[4];
    float* out = (float*)d_out;

    const int nvec = n >> 2;
    const int block = 1024;
    if (nvec > 0) {
        int grid = (nvec + block - 1) / block;
        if (grid > 512) grid = 512;      // 2 blocks/CU (LDS-limited) x 256 CU
        div_q16_main<<<grid, block, 0, stream>>>(
            (const int4*)q1, (const int4*)q2, s1, s2, os, (float4*)out, nvec);
    }
    const int tail = n & 3;
    if (tail) {
        div_q16_tail<<<1, block, 0, stream>>>(q1, q2, s1, s2, os, out,
                                              n - tail, n);
    }
}

// Round 5
// 164.440 us; speedup vs baseline: 1.0986x; 1.0986x over previous
//
#include <hip/hip_runtime.h>

// Div (quantized qint16) vs float64 numpy reference.
//
// out = clip(round(q1*s1 * (recip_q(q2*s2)*TS) / os)), recip_q = piecewise
// {const, line, dense LUT(256), sparse LUT(256), line, const} of 1/|x|, signed.
//
// recip_q depends only on |q2| -> uint16 LUT[32768] (values integer in
// [15,32767]; |q2|=32768 clamps to 32767 = same sparse idx 236 -> same rq).
// r4 regression post-mortem: per-block LUT build (512 redundant f64 builds)
// + 1-deep pipeline (VGPR=16!) kept the kernel latency-bound (VALU 25%,
// HBM 16%). r5: build LUT ONCE into d_ws with a 2us kernel; main kernel
// copies it to LDS with 4 coalesced uint4 reads/thread, then streams with
// a x2-unrolled loop (4 int4 loads in flight before any use).
//
// Numerics unchanged from the passing r3/r4 (absmax 384 / 655 threshold):
// f64 index math + f64 linspace/divides in the LUT builder; f32 finals
// (<=+-1 output unit of slack).

#define TS64  (2.0 / 0.01 / 65535.0)     // f64 of Python 2/0.01/65535
#define STEPD (0.99 / 255.0)
#define STEPS (6.0 / 255.0)

__device__ __forceinline__ double quant64(double y) {
    return fmin(fmax(rint(y / TS64), -32768.0), 32767.0);
}

// f64 piecewise recip-quant per |q2| value (aq >= 0). Bit-matches np-f64 ref.
__device__ double rq_of_aq(int aq, double s2d) {
    const double ax = (double)aq * s2d;            // EXACT in f64
    double rq;
    if (ax < 0.01) {
        rq = 32767.0;                    // left const + left line both saturate
    } else if (ax < 7.0) {
        const bool dense = ax < 1.0;
        const double xmin = dense ? 0.01 : 1.0;
        const double step = dense ? STEPD : STEPS;
        double idx = rint((ax - xmin) / step);     // IEEE f64 divide
        idx = fmin(fmax(idx, 0.0), 255.0);
        double xs;
        if (idx == 255.0) {
            xs = dense ? 1.0 : 7.0;                // np.linspace endpoint
        } else {
            double p = idx * step;                 // linspace: round product,
            asm volatile("" : "+v"(p));            // block fma contraction,
            xs = xmin + p;                         // then add start
        }
        rq = quant64(1.0 / xs);
    } else if (ax < 20.0) {
        rq = quant64(1.0 / 7.0 + (ax - 7.0) * ((0.05 - 1.0 / 7.0) / 13.0));
    } else {
        rq = 16.0;                                 // quant(1/20)
    }
    return rq;
}

__global__ void __launch_bounds__(256)
build_lut_kernel(unsigned short* __restrict__ lut, const float* __restrict__ s2p) {
    const int t = blockIdx.x * 256 + threadIdx.x;
    if (t < 32768) lut[t] = (unsigned short)(int)rq_of_aq(t, (double)s2p[0]);
}

__device__ __forceinline__ float elem(int a, int b, float kf,
                                      const unsigned short* tbl) {
    const int aq = min(abs(b), 32767);
    float rq = (float)tbl[aq];           // ds_read_u16; exact int in [15,32767]
    rq = (b < 0) ? -rq : rq;
    const float o = rintf((float)a * kf * rq);
    return fminf(fmaxf(o, -32768.0f), 32767.0f);
}

template <bool SELF_BUILD>
__global__ void __launch_bounds__(1024)
div_q16_main(const int4* __restrict__ q1, const int4* __restrict__ q2,
             const uint4* __restrict__ lutg, const float* __restrict__ s1p,
             const float* __restrict__ s2p, const float* __restrict__ osp,
             float4* __restrict__ out, int nvec) {
    __shared__ unsigned short tbl[32768];          // 64 KiB -> 2 blocks/CU
    if constexpr (SELF_BUILD) {                    // fallback if ws too small
        const double s2d = (double)s2p[0];
        for (int t = threadIdx.x; t < 32768; t += 1024)
            tbl[t] = (unsigned short)(int)rq_of_aq(t, s2d);
    } else {                                       // 4 coalesced uint4 / thread
        uint4* ls = (uint4*)tbl;
#pragma unroll
        for (int p = 0; p < 4; ++p)
            ls[p * 1024 + threadIdx.x] = lutg[p * 1024 + threadIdx.x];
    }
    __syncthreads();

    const float kf = (float)((double)s1p[0] * TS64 / (double)osp[0]);
    const int stride = gridDim.x * blockDim.x;     // 524288
    int i = blockIdx.x * blockDim.x + threadIdx.x;

    // x2 unrolled stream: all 4 loads issued before any use (b first: the
    // LDS-gather chain hangs off b, so its vmcnt retires earliest).
    for (; i + stride < nvec; i += 2 * stride) {
        const int4 b0 = q2[i];
        const int4 b1 = q2[i + stride];
        const int4 a0 = q1[i];
        const int4 a1 = q1[i + stride];
        float4 o0, o1;
        o0.x = elem(a0.x, b0.x, kf, tbl);
        o0.y = elem(a0.y, b0.y, kf, tbl);
        o0.z = elem(a0.z, b0.z, kf, tbl);
        o0.w = elem(a0.w, b0.w, kf, tbl);
        out[i] = o0;
        o1.x = elem(a1.x, b1.x, kf, tbl);
        o1.y = elem(a1.y, b1.y, kf, tbl);
        o1.z = elem(a1.z, b1.z, kf, tbl);
        o1.w = elem(a1.w, b1.w, kf, tbl);
        out[i + stride] = o1;
    }
    for (; i < nvec; i += stride) {
        const int4 a = q1[i];
        const int4 b = q2[i];
        float4 o;
        o.x = elem(a.x, b.x, kf, tbl);
        o.y = elem(a.y, b.y, kf, tbl);
        o.z = elem(a.z, b.z, kf, tbl);
        o.w = elem(a.w, b.w, kf, tbl);
        out[i] = o;
    }
}

__global__ void __launch_bounds__(64)
div_q16_tail(const int* __restrict__ q1, const int* __restrict__ q2,
             const unsigned short* __restrict__ lut,
             const float* __restrict__ s1p, const float* __restrict__ osp,
             float* __restrict__ out, int base, int n) {
    const float kf = (float)((double)s1p[0] * TS64 / (double)osp[0]);
    const int i = base + (int)threadIdx.x;
    if (i < n) out[i] = elem(q1[i], q2[i], kf, lut);   // global gather, <=3 elems
}

extern "C" void kernel_launch(void* const* d_in, const int* in_sizes, int n_in,
                              void* d_out, int out_size, void* d_ws, size_t ws_size,
                              hipStream_t stream) {
    const int n = in_sizes[0];
    const int* q1 = (const int*)d_in[0];
    const int* q2 = (const int*)d_in[1];
    const float* s1 = (const float*)d_in[2];
    const float* s2 = (const float*)d_in[3];
    const float* os = (const float*)d_in[4];
    float* out = (float*)d_out;

    const bool have_ws = ws_size >= 32768u * sizeof(unsigned short);
    unsigned short* lut = (unsigned short*)d_ws;

    if (have_ws)
        build_lut_kernel<<<128, 256, 0, stream>>>(lut, s2);

    const int nvec = n >> 2;
    const int block = 1024;
    if (nvec > 0) {
        int grid = (nvec + block - 1) / block;
        if (grid > 512) grid = 512;      // 2 blocks/CU (64 KiB LDS) x 256 CU
        if (have_ws)
            div_q16_main<false><<<grid, block, 0, stream>>>(
                (const int4*)q1, (const int4*)q2, (const uint4*)lut,
                s1, s2, os, (float4*)out, nvec);
        else
            div_q16_main<true><<<grid, block, 0, stream>>>(
                (const int4*)q1, (const int4*)q2, nullptr,
                s1, s2, os, (float4*)out, nvec);
    }
    const int tail = n & 3;
    if (tail && have_ws) {
        div_q16_tail<<<1, 64, 0, stream>>>(q1, q2, lut, s1, os, out,
                                           n - tail, n);
    } else if (tail) {
        // no-ws fallback for the (unused here) non-multiple-of-4 case:
        div_q16_main<true><<<1, block, 0, stream>>>(
            (const int4*)q1, (const int4*)q2, nullptr, s1, s2, os,
            (float4*)out, 0);  // build only; then scalar pass below
        // handle tail scalars via a tiny self-building main variant is
        // unnecessary for this problem (n % 4 == 0); left intentionally.
    }
}

// Round 6
// 162.122 us; speedup vs baseline: 1.1143x; 1.0143x over previous
//
#include <hip/hip_runtime.h>

// Div (quantized qint16) vs float64 numpy reference.
//
// out = clip(round(q1*s1 * (recip_q(q2*s2)*TS) / os)); recip_q = piecewise
// {const, line, dense LUT(256), sparse LUT(256), line, const} of 1/|x|, signed.
// recip_q depends only on |q2| -> uint16 LUT[32768] built once in d_ws with
// exact f64 math (bit-matches np-f64 ref; values are ints in [15,32767];
// |q2|=32768 clamps to 32767 = same sparse idx 236 -> same rq).
//
// r5 post-mortem: two different compute strategies (per-elem f64 chain vs LDS
// LUT) both land at 164us, VALU 12%, HBM 35% -> latency x MLP bound, not
// compute. BWxlatency needs ~9 KB outstanding/CU; r5 had ~2 KB/wave.
// r6: x4 unroll, all 8 int4 loads issued then PINNED with sched_barrier(0)
// (compiler provably re-serializes otherwise: r5 VGPR=20), + nontemporal
// stores so the write stream stops evicting the L3-resident inputs
// (FETCH showed L3 already serves ~half the reads).

typedef int   __attribute__((ext_vector_type(4))) i32x4;
typedef float __attribute__((ext_vector_type(4))) f32x4;

#define TS64  (2.0 / 0.01 / 65535.0)
#define STEPD (0.99 / 255.0)
#define STEPS (6.0 / 255.0)

__device__ __forceinline__ double quant64(double y) {
    return fmin(fmax(rint(y / TS64), -32768.0), 32767.0);
}

// f64 piecewise recip-quant per |q2| value (aq >= 0). Bit-matches np-f64 ref.
__device__ double rq_of_aq(int aq, double s2d) {
    const double ax = (double)aq * s2d;            // EXACT in f64
    double rq;
    if (ax < 0.01) {
        rq = 32767.0;                    // left const + left line both saturate
    } else if (ax < 7.0) {
        const bool dense = ax < 1.0;
        const double xmin = dense ? 0.01 : 1.0;
        const double step = dense ? STEPD : STEPS;
        double idx = rint((ax - xmin) / step);     // IEEE f64 divide
        idx = fmin(fmax(idx, 0.0), 255.0);
        double xs;
        if (idx == 255.0) {
            xs = dense ? 1.0 : 7.0;                // np.linspace endpoint
        } else {
            double p = idx * step;                 // linspace: round product,
            asm volatile("" : "+v"(p));            // block fma contraction,
            xs = xmin + p;                         // then add start
        }
        rq = quant64(1.0 / xs);
    } else if (ax < 20.0) {
        rq = quant64(1.0 / 7.0 + (ax - 7.0) * ((0.05 - 1.0 / 7.0) / 13.0));
    } else {
        rq = 16.0;                                 // quant(1/20)
    }
    return rq;
}

__global__ void __launch_bounds__(256)
build_lut_kernel(unsigned short* __restrict__ lut, const float* __restrict__ s2p) {
    const int t = blockIdx.x * 256 + threadIdx.x;
    if (t < 32768) lut[t] = (unsigned short)(int)rq_of_aq(t, (double)s2p[0]);
}

__device__ __forceinline__ float elem(int a, int b, float kf,
                                      const unsigned short* tbl) {
    const int aq = min(abs(b), 32767);
    float rq = (float)tbl[aq];           // ds_read_u16; exact int in [15,32767]
    rq = (b < 0) ? -rq : rq;
    const float o = rintf((float)a * kf * rq);
    return fminf(fmaxf(o, -32768.0f), 32767.0f);
}

__device__ __forceinline__ f32x4 calc4(i32x4 a, i32x4 b, float kf,
                                       const unsigned short* tbl) {
    f32x4 o;
    o.x = elem(a.x, b.x, kf, tbl);
    o.y = elem(a.y, b.y, kf, tbl);
    o.z = elem(a.z, b.z, kf, tbl);
    o.w = elem(a.w, b.w, kf, tbl);
    return o;
}

template <bool SELF_BUILD>
__global__ void __launch_bounds__(1024)
div_q16_main(const i32x4* __restrict__ q1, const i32x4* __restrict__ q2,
             const uint4* __restrict__ lutg, const float* __restrict__ s1p,
             const float* __restrict__ s2p, const float* __restrict__ osp,
             f32x4* __restrict__ out, int nvec) {
    __shared__ unsigned short tbl[32768];          // 64 KiB
    if constexpr (SELF_BUILD) {
        const double s2d = (double)s2p[0];
        for (int t = threadIdx.x; t < 32768; t += 1024)
            tbl[t] = (unsigned short)(int)rq_of_aq(t, s2d);
    } else {                                       // 4 coalesced uint4/thread
        uint4* ls = (uint4*)tbl;
#pragma unroll
        for (int p = 0; p < 4; ++p)
            ls[p * 1024 + threadIdx.x] = lutg[p * 1024 + threadIdx.x];
    }
    __syncthreads();

    const float kf = (float)((double)s1p[0] * TS64 / (double)osp[0]);
    const int stride = gridDim.x * blockDim.x;
    int i = blockIdx.x * blockDim.x + threadIdx.x;

    // x4 unrolled: 8 loads (8 KB/wave) in flight before any use; the
    // sched_barrier(0) pins the load cluster above the compute so the
    // compiler cannot re-serialize it (r4/r5 lesson, VGPR=16/20).
    for (; i + 3 * stride < nvec; i += 4 * stride) {
        const i32x4 b0 = q2[i];
        const i32x4 b1 = q2[i + stride];
        const i32x4 b2 = q2[i + 2 * stride];
        const i32x4 b3 = q2[i + 3 * stride];
        const i32x4 a0 = q1[i];
        const i32x4 a1 = q1[i + stride];
        const i32x4 a2 = q1[i + 2 * stride];
        const i32x4 a3 = q1[i + 3 * stride];
        __builtin_amdgcn_sched_barrier(0);
        // nontemporal: the output stream must not evict L3-resident inputs
        __builtin_nontemporal_store(calc4(a0, b0, kf, tbl), &out[i]);
        __builtin_nontemporal_store(calc4(a1, b1, kf, tbl), &out[i + stride]);
        __builtin_nontemporal_store(calc4(a2, b2, kf, tbl), &out[i + 2 * stride]);
        __builtin_nontemporal_store(calc4(a3, b3, kf, tbl), &out[i + 3 * stride]);
    }
    for (; i < nvec; i += stride) {
        const i32x4 a = q1[i];
        const i32x4 b = q2[i];
        __builtin_nontemporal_store(calc4(a, b, kf, tbl), &out[i]);
    }
}

__global__ void __launch_bounds__(64)
div_q16_tail(const int* __restrict__ q1, const int* __restrict__ q2,
             const unsigned short* __restrict__ lut,
             const float* __restrict__ s1p, const float* __restrict__ osp,
             float* __restrict__ out, int base, int n) {
    const float kf = (float)((double)s1p[0] * TS64 / (double)osp[0]);
    const int i = base + (int)threadIdx.x;
    if (i < n) out[i] = elem(q1[i], q2[i], kf, lut);   // <=3 elems, global gather
}

extern "C" void kernel_launch(void* const* d_in, const int* in_sizes, int n_in,
                              void* d_out, int out_size, void* d_ws, size_t ws_size,
                              hipStream_t stream) {
    const int n = in_sizes[0];
    const int* q1 = (const int*)d_in[0];
    const int* q2 = (const int*)d_in[1];
    const float* s1 = (const float*)d_in[2];
    const float* s2 = (const float*)d_in[3];
    const float* os = (const float*)d_in[4];
    float* out = (float*)d_out;

    const bool have_ws = ws_size >= 32768u * sizeof(unsigned short);
    unsigned short* lut = (unsigned short*)d_ws;

    if (have_ws)
        build_lut_kernel<<<128, 256, 0, stream>>>(lut, s2);

    const int nvec = n >> 2;
    const int block = 1024;
    if (nvec > 0) {
        int grid = (nvec + block - 1) / block;
        if (grid > 512) grid = 512;      // 2 blocks/CU (64 KiB LDS) x 256 CU
        if (have_ws)
            div_q16_main<false><<<grid, block, 0, stream>>>(
                (const i32x4*)q1, (const i32x4*)q2, (const uint4*)lut,
                s1, s2, os, (f32x4*)out, nvec);
        else
            div_q16_main<true><<<grid, block, 0, stream>>>(
                (const i32x4*)q1, (const i32x4*)q2, nullptr,
                s1, s2, os, (f32x4*)out, nvec);
    }
    const int tail = n & 3;
    if (tail && have_ws) {
        div_q16_tail<<<1, 64, 0, stream>>>(q1, q2, lut, s1, os, out,
                                           n - tail, n);
    }
}

// Round 7
// 150.833 us; speedup vs baseline: 1.1977x; 1.0748x over previous
//
#include <hip/hip_runtime.h>

// Div (quantized qint16) vs float64 numpy reference.
//
// out = clip(round(q1*s1 * (recip_q(q2*s2)*TS) / os)); recip_q = piecewise
// {const, line, dense LUT(256), sparse LUT(256), line, const} of 1/|x|, signed.
// recip_q depends only on |q2| -> uint16 LUT[32768] built once in d_ws with
// exact f64 math (bit-matches np-f64 ref; values are ints in [15,32767];
// |q2|=32768 clamps to 32767 = same sparse idx 236 -> same rq).
//
// r6 post-mortem: MLP theory falsified (a dwordx4 load is 1 KiB/wave-instr;
// outstanding bytes were always >> BWxlatency). Three orthogonal structures
// all land 162-164us = 4.97 TB/s app-side (79% of copy ceiling), with HBM
// 3.2/6.3 TB/s, VALU 11%, LDS ~nil -- nothing saturated. Remaining suspect:
// steady-state L3 thrash (FETCH=256MiB proves half the 512MiB input re-reads
// hit L3; the 256MiB/replay write stream keeps evicting the other half;
// nt-STORE alone changed nothing). r7 single-variable A/B vs r6: loads are
// ALSO nontemporal (evict-first -> inputs stop churning L3; reads become a
// clean HBM stream). Predict: FETCH -> ~512MiB; dur 135-150 if theory right,
// 158-165 if read-path-concurrency-bound (then we are at practical roofline).

typedef int   __attribute__((ext_vector_type(4))) i32x4;
typedef float __attribute__((ext_vector_type(4))) f32x4;

#define TS64  (2.0 / 0.01 / 65535.0)
#define STEPD (0.99 / 255.0)
#define STEPS (6.0 / 255.0)

__device__ __forceinline__ double quant64(double y) {
    return fmin(fmax(rint(y / TS64), -32768.0), 32767.0);
}

// f64 piecewise recip-quant per |q2| value (aq >= 0). Bit-matches np-f64 ref.
__device__ double rq_of_aq(int aq, double s2d) {
    const double ax = (double)aq * s2d;            // EXACT in f64
    double rq;
    if (ax < 0.01) {
        rq = 32767.0;                    // left const + left line both saturate
    } else if (ax < 7.0) {
        const bool dense = ax < 1.0;
        const double xmin = dense ? 0.01 : 1.0;
        const double step = dense ? STEPD : STEPS;
        double idx = rint((ax - xmin) / step);     // IEEE f64 divide
        idx = fmin(fmax(idx, 0.0), 255.0);
        double xs;
        if (idx == 255.0) {
            xs = dense ? 1.0 : 7.0;                // np.linspace endpoint
        } else {
            double p = idx * step;                 // linspace: round product,
            asm volatile("" : "+v"(p));            // block fma contraction,
            xs = xmin + p;                         // then add start
        }
        rq = quant64(1.0 / xs);
    } else if (ax < 20.0) {
        rq = quant64(1.0 / 7.0 + (ax - 7.0) * ((0.05 - 1.0 / 7.0) / 13.0));
    } else {
        rq = 16.0;                                 // quant(1/20)
    }
    return rq;
}

__global__ void __launch_bounds__(256)
build_lut_kernel(unsigned short* __restrict__ lut, const float* __restrict__ s2p) {
    const int t = blockIdx.x * 256 + threadIdx.x;
    if (t < 32768) lut[t] = (unsigned short)(int)rq_of_aq(t, (double)s2p[0]);
}

__device__ __forceinline__ float elem(int a, int b, float kf,
                                      const unsigned short* tbl) {
    const int aq = min(abs(b), 32767);
    float rq = (float)tbl[aq];           // ds_read_u16; exact int in [15,32767]
    rq = (b < 0) ? -rq : rq;
    const float o = rintf((float)a * kf * rq);
    return fminf(fmaxf(o, -32768.0f), 32767.0f);
}

__device__ __forceinline__ f32x4 calc4(i32x4 a, i32x4 b, float kf,
                                       const unsigned short* tbl) {
    f32x4 o;
    o.x = elem(a.x, b.x, kf, tbl);
    o.y = elem(a.y, b.y, kf, tbl);
    o.z = elem(a.z, b.z, kf, tbl);
    o.w = elem(a.w, b.w, kf, tbl);
    return o;
}

template <bool SELF_BUILD>
__global__ void __launch_bounds__(1024)
div_q16_main(const i32x4* __restrict__ q1, const i32x4* __restrict__ q2,
             const uint4* __restrict__ lutg, const float* __restrict__ s1p,
             const float* __restrict__ s2p, const float* __restrict__ osp,
             f32x4* __restrict__ out, int nvec) {
    __shared__ unsigned short tbl[32768];          // 64 KiB
    if constexpr (SELF_BUILD) {
        const double s2d = (double)s2p[0];
        for (int t = threadIdx.x; t < 32768; t += 1024)
            tbl[t] = (unsigned short)(int)rq_of_aq(t, s2d);
    } else {                                       // 4 coalesced uint4/thread
        uint4* ls = (uint4*)tbl;
#pragma unroll
        for (int p = 0; p < 4; ++p)
            ls[p * 1024 + threadIdx.x] = lutg[p * 1024 + threadIdx.x];
    }
    __syncthreads();

    const float kf = (float)((double)s1p[0] * TS64 / (double)osp[0]);
    const int stride = gridDim.x * blockDim.x;
    int i = blockIdx.x * blockDim.x + threadIdx.x;

    // nontemporal on BOTH streams: inputs are read once per pass and must not
    // churn L3 against the write stream (r7's single-variable change vs r6).
    for (; i + 3 * stride < nvec; i += 4 * stride) {
        const i32x4 b0 = __builtin_nontemporal_load(&q2[i]);
        const i32x4 b1 = __builtin_nontemporal_load(&q2[i + stride]);
        const i32x4 b2 = __builtin_nontemporal_load(&q2[i + 2 * stride]);
        const i32x4 b3 = __builtin_nontemporal_load(&q2[i + 3 * stride]);
        const i32x4 a0 = __builtin_nontemporal_load(&q1[i]);
        const i32x4 a1 = __builtin_nontemporal_load(&q1[i + stride]);
        const i32x4 a2 = __builtin_nontemporal_load(&q1[i + 2 * stride]);
        const i32x4 a3 = __builtin_nontemporal_load(&q1[i + 3 * stride]);
        __builtin_nontemporal_store(calc4(a0, b0, kf, tbl), &out[i]);
        __builtin_nontemporal_store(calc4(a1, b1, kf, tbl), &out[i + stride]);
        __builtin_nontemporal_store(calc4(a2, b2, kf, tbl), &out[i + 2 * stride]);
        __builtin_nontemporal_store(calc4(a3, b3, kf, tbl), &out[i + 3 * stride]);
    }
    for (; i < nvec; i += stride) {
        const i32x4 a = __builtin_nontemporal_load(&q1[i]);
        const i32x4 b = __builtin_nontemporal_load(&q2[i]);
        __builtin_nontemporal_store(calc4(a, b, kf, tbl), &out[i]);
    }
}

__global__ void __launch_bounds__(64)
div_q16_tail(const int* __restrict__ q1, const int* __restrict__ q2,
             const unsigned short* __restrict__ lut,
             const float* __restrict__ s1p, const float* __restrict__ osp,
             float* __restrict__ out, int base, int n) {
    const float kf = (float)((double)s1p[0] * TS64 / (double)osp[0]);
    const int i = base + (int)threadIdx.x;
    if (i < n) out[i] = elem(q1[i], q2[i], kf, lut);   // <=3 elems, global gather
}

extern "C" void kernel_launch(void* const* d_in, const int* in_sizes, int n_in,
                              void* d_out, int out_size, void* d_ws, size_t ws_size,
                              hipStream_t stream) {
    const int n = in_sizes[0];
    const int* q1 = (const int*)d_in[0];
    const int* q2 = (const int*)d_in[1];
    const float* s1 = (const float*)d_in[2];
    const float* s2 = (const float*)d_in[3];
    const float* os = (const float*)d_in[4];
    float* out = (float*)d_out;

    const bool have_ws = ws_size >= 32768u * sizeof(unsigned short);
    unsigned short* lut = (unsigned short*)d_ws;

    if (have_ws)
        build_lut_kernel<<<128, 256, 0, stream>>>(lut, s2);

    const int nvec = n >> 2;
    const int block = 1024;
    if (nvec > 0) {
        int grid = (nvec + block - 1) / block;
        if (grid > 512) grid = 512;      // 2 blocks/CU (64 KiB LDS) x 256 CU
        if (have_ws)
            div_q16_main<false><<<grid, block, 0, stream>>>(
                (const i32x4*)q1, (const i32x4*)q2, (const uint4*)lut,
                s1, s2, os, (f32x4*)out, nvec);
        else
            div_q16_main<true><<<grid, block, 0, stream>>>(
                (const i32x4*)q1, (const i32x4*)q2, nullptr,
                s1, s2, os, (f32x4*)out, nvec);
    }
    const int tail = n & 3;
    if (tail && have_ws) {
        div_q16_tail<<<1, 64, 0, stream>>>(q1, q2, lut, s1, os, out,
                                           n - tail, n);
    }
}